// Round 2
// baseline (12123.830 us; speedup 1.0000x reference)
//
#include <hip/hip_runtime.h>

// ZoneoutGRU persistent kernel v9: B=64, T=1024, IN=512, H=1024, L=2, zo=0.1.
// 128 active blocks (64 LA = layer0, 64 LB = layer1), 256 thr (4 waves = K
// slices). Weights VGPR-resident, fp32 h state in registers. Deep h rings
// (v7): consumer reads are L2-cacheable (sc0), no stale-L2 hazard.
// v9 vs v8: attack the serial handshake chain (H2: poll-storm congestion at
// MALL + fully-serial per-step structure).
//  - LA: x-GEMM moved BEFORE the CA/CB spins (x is pure input).
//  - LB: a-GEMM (gated only by CA[s], produced ~256 steps earlier by LA)
//    moved BEFORE the CB[s-1] spin => CB flag arrives during a-GEMM.
//  - LB: CA read-ahead cache — poll CA[s+32] once per ~32 steps instead of
//    exact-spinning CA[s] each step (halves steady-state poll traffic).
//  - spin_ge: first poll immediate, then s_sleep(8) backoff (~4-8x fewer
//    poll transactions; cuts MALL queueing on the 16 hot counter lines).
//  - pads (DVFS insurance) kept but poll cadence cut 16x, barriers rarer.
// Protocol invariants preserved: every ring read still behind its flag spin
// + __syncthreads; sibling-block lag stays <= 1 step; ring-overwrite guards
// unchanged (LA: CB[s-256]; LB: self-chain).

#define Tn 1024
#define Hn 1024
#define INn 512

typedef short s8v __attribute__((ext_vector_type(8)));
typedef float f4v __attribute__((ext_vector_type(4)));
typedef unsigned short us4v __attribute__((ext_vector_type(4)));
typedef unsigned long long ull;

// ws layout (bytes) — total 168,837,120 (~161 MB)
#define WS_XB  0u           // x bf16 [64][1024][512]            = 67,108,864
#define WS_H0R 67108864u    // ring [512][ktile64][b64][16] bf16 = 67,108,864
#define WS_H1R 134217728u   // ring [256][ktile64][b64][16] bf16 = 33,554,432
#define WS_CA  167772160u   // [1040][128] int (8 banks @ 64B)   =    532,480
#define WS_CB  168304640u   // same                              =    532,480

__device__ __forceinline__ unsigned short f2bf(float f) {
  unsigned int u = __float_as_uint(f);
  u += 0x7fffu + ((u >> 16) & 1u);
  return (unsigned short)(u >> 16);
}

__device__ __forceinline__ s8v pack8(const float* p) {
  float4 a = *(const float4*)p;
  float4 b = *(const float4*)(p + 4);
  s8v r;
  r[0] = (short)f2bf(a.x); r[1] = (short)f2bf(a.y);
  r[2] = (short)f2bf(a.z); r[3] = (short)f2bf(a.w);
  r[4] = (short)f2bf(b.x); r[5] = (short)f2bf(b.y);
  r[6] = (short)f2bf(b.z); r[7] = (short)f2bf(b.w);
  return r;
}

// producer store: relaxed agent-scope 8B atomic = write-through to MALL (v3+)
__device__ __forceinline__ void st8c(unsigned short* p, us4v v) {
  union { us4v v; ull u; } c; c.v = v;
  __hip_atomic_store((ull*)p, c.u, __ATOMIC_RELAXED, __HIP_MEMORY_SCOPE_AGENT);
}

// consumer loads: sc0 only — L1-bypass, L2-CACHEABLE (deep ring => no stale)
__device__ __forceinline__ void issue4c(s8v* f, const unsigned short* src,
                                        int kt, int w, int rl, int kg) {
#pragma unroll
  for (int m = 0; m < 4; ++m) {
    const unsigned short* p = src + (size_t)(w * 16 + kt * 2 + (kg >> 1)) * 1024
                              + (m * 16 + rl) * 16 + (kg & 1) * 8;
    asm volatile("global_load_dwordx4 %0, %1, off sc0"
                 : "=v"(f[m]) : "v"(p) : "memory");
  }
}

#define VMWAIT(n) do { asm volatile("s_waitcnt vmcnt(" #n ")" ::: "memory"); \
                       __builtin_amdgcn_sched_barrier(0); } while (0)

__device__ __forceinline__ void mfma3(f4v (*acc)[4], s8v w0, s8v w1, s8v w2,
                                      const s8v f[4], const int gl) {
#pragma unroll
  for (int m = 0; m < 4; ++m) {
    acc[m][0]  = __builtin_amdgcn_mfma_f32_16x16x32_bf16(w0, f[m], acc[m][0], 0, 0, 0);
    acc[m][1]  = __builtin_amdgcn_mfma_f32_16x16x32_bf16(w1, f[m], acc[m][1], 0, 0, 0);
    acc[m][gl] = __builtin_amdgcn_mfma_f32_16x16x32_bf16(w2, f[m], acc[m][gl], 0, 0, 0);
  }
}

// v4-proven 2-deep pipelined stream GEMM: 8 k-tiles, fA/fB alternation.
// Precondition: vmcnt == 0 on entry (self-drains on exit).
template<int GL>
__device__ __forceinline__ void stream_gemm(f4v (*acc)[4], const s8v (*wgt)[8],
    const unsigned short* src, int w, int rl, int kg) {
  s8v fA[4], fB[4];
  issue4c(fA, src, 0, w, rl, kg);
#pragma unroll
  for (int kt = 0; kt < 8; kt += 2) {
    issue4c(fB, src, kt + 1, w, rl, kg);
    VMWAIT(4);                              // fA complete (fB outstanding)
    mfma3(acc, wgt[0][kt], wgt[1][kt], wgt[2][kt], fA, GL);
    if (kt + 2 < 8) {
      issue4c(fA, src, kt + 2, w, rl, kg);
      VMWAIT(4);                            // fB complete (fA outstanding)
    } else {
      VMWAIT(0);                            // drain
    }
    mfma3(acc, wgt[0][kt + 1], wgt[1][kt + 1], wgt[2][kt + 1], fB, GL);
  }
}

__global__ void cvt_bf16_kernel(const float* __restrict__ src,
                                unsigned short* __restrict__ dst, int n4) {
  int i = blockIdx.x * blockDim.x + threadIdx.x;
  int st = gridDim.x * blockDim.x;
  for (; i < n4; i += st) {
    const float4 v = *(const float4*)(src + 4 * (size_t)i);
    us4v o;
    o[0] = f2bf(v.x); o[1] = f2bf(v.y); o[2] = f2bf(v.z); o[3] = f2bf(v.w);
    *(us4v*)(dst + 4 * (size_t)i) = o;
  }
}

__global__ void init_all(const float* __restrict__ h0in, char* __restrict__ ws) {
  int i = blockIdx.x * blockDim.x + threadIdx.x;   // grid 528*256 = 135168
  unsigned short* h0r = (unsigned short*)(ws + WS_H0R);
  unsigned short* h1r = (unsigned short*)(ws + WS_H1R);
  int* CA = (int*)(ws + WS_CA);
  int* CB = (int*)(ws + WS_CB);
  if (i < 65536) {
    int b = i >> 10, h = i & 1023;
    int off = (h >> 4) * 1024 + b * 16 + (h & 15);
    h0r[511 * 65536 + off] = f2bf(h0in[i]);          // slot for step -1
    h1r[255 * 65536 + off] = f2bf(h0in[65536 + i]);  // slot for step -1
  }
  if (i < 133120) {
    int v = ((i >> 7) < 16 && (i & 15) == 0) ? 8 : 0;
    CA[i] = v; CB[i] = v;
  }
}

// v9: first poll immediate (steady state: flag already set => 1 MALL read);
// retries backed off with s_sleep(8) (~512 cy) to cut MALL queue pressure.
__device__ __forceinline__ void spin_ge(int* p, int target) {
  if (__hip_atomic_load(p, __ATOMIC_RELAXED, __HIP_MEMORY_SCOPE_AGENT) >= target)
    return;
  int tries = 0;
  for (;;) {
    __builtin_amdgcn_s_sleep(8);
    if (__hip_atomic_load(p, __ATOMIC_RELAXED, __HIP_MEMORY_SCOPE_AGENT) >= target)
      return;
    if (++tries > (1 << 20)) return;   // fail visibly, never hang
  }
}

// counter dword index for step s (>= -16), bank k
#define CDW(s, k) (((s) + 16) * 128 + (k) * 16)

__global__ __launch_bounds__(256, 1) void gru_persist(
    const float* __restrict__ h0in,
    const float* __restrict__ wih0, const float* __restrict__ whh0,
    const float* __restrict__ bih0, const float* __restrict__ bhh0,
    const float* __restrict__ wih1, const float* __restrict__ whh1,
    const float* __restrict__ bih1, const float* __restrict__ bhh1,
    float* __restrict__ out, char* __restrict__ ws)
{
  const unsigned short* xb = (const unsigned short*)(ws + WS_XB);
  unsigned short* h0r = (unsigned short*)(ws + WS_H0R);
  unsigned short* h1r = (unsigned short*)(ws + WS_H1R);
  int* CA = (int*)(ws + WS_CA);
  int* CB = (int*)(ws + WS_CB);

  const int blk = blockIdx.x;
  const int tid = threadIdx.x;

  if (blk >= 128) {
    // busy-clock pad (DVFS insurance). v9: poll cadence cut 16x (~32K cy),
    // barriers only around the rare poll => near-zero MALL/LDS traffic.
    __shared__ int sdone;
    if (tid == 0) sdone = 0;
    __syncthreads();
    float a0 = 1.0f + (float)tid * 1e-6f, a1 = a0 + 0.25f;
    float a2 = a0 + 0.5f, a3 = a0 + 0.75f;
    const float m = 0.99999988f, c = 1e-7f;
    int kcur = 0;
    for (int it = 0; it < (1 << 18) && kcur < 8; ++it) {
#pragma unroll
      for (int u = 0; u < 256; ++u) {
        a0 = __builtin_fmaf(a0, m, c); a1 = __builtin_fmaf(a1, m, c);
        a2 = __builtin_fmaf(a2, m, c); a3 = __builtin_fmaf(a3, m, c);
      }
      if ((it & 15) == 0) {
        if (tid == 0 &&
            __hip_atomic_load(&CB[CDW(Tn - 1, kcur)], __ATOMIC_RELAXED,
                              __HIP_MEMORY_SCOPE_AGENT) >= 8)
          sdone = kcur + 1;
        __syncthreads();
        kcur = sdone;        // uniform across the block
        __syncthreads();     // protect sdone write of next poll
      }
    }
    asm volatile("" :: "v"(a0), "v"(a1), "v"(a2), "v"(a3));  // keep chains live
    return;
  }

  const bool isA = blk < 64;
  const int jt = blk & 63, jj = jt * 16;
  const int w = tid >> 6;                    // wave = K-slice = owner m-group
  const int lane = tid & 63;
  const int rl = lane & 15, kg = lane >> 4;
  const int bank = blk & 7;

  __shared__ float cmb[4][4][64][20];        // stride 80B: conflict-free (r6)

  const int b = w * 16 + rl;                 // owner batch row (epilogue)
  const int j0 = jj + kg * 4;                // owner j base (epilogue)

  // ---- VGPR-resident weights ----
  const float* Wi = isA ? wih0 : wih1;
  const float* Wh = isA ? whh0 : whh1;
  const float* bi = isA ? bih0 : bih1;
  const float* bh = isA ? bhh0 : bhh1;
  const int Kx = isA ? INn : Hn;             // input-side K
  s8v wx[3][8], wh_[3][8];
  const int nkx = Kx / 128;                  // 4 (LA) or 8 (LB) k-tiles of 32
#pragma unroll
  for (int g = 0; g < 3; ++g) {
    for (int kt = 0; kt < nkx; ++kt)
      wx[g][kt] = pack8(Wi + (size_t)(g * 1024 + jj + rl) * Kx + w * (Kx / 4) + kt * 32 + kg * 8);
#pragma unroll
    for (int kt = 0; kt < 8; ++kt)
      wh_[g][kt] = pack8(Wh + (size_t)(g * 1024 + jj + rl) * Hn + w * 256 + kt * 32 + kg * 8);
  }
  const f4v bir = *(const f4v*)(bi + j0),        bhr = *(const f4v*)(bh + j0);
  const f4v biz = *(const f4v*)(bi + 1024 + j0), bhz = *(const f4v*)(bh + 1024 + j0);
  const f4v bin = *(const f4v*)(bi + 2048 + j0), bhn = *(const f4v*)(bh + 2048 + j0);

  // ---- register-resident fp32 hidden state (this thread's (b, j0..j0+3)) ----
  f4v hv = *(const f4v*)(h0in + (isA ? 0u : 65536u) + (size_t)b * Hn + j0);

  int caDone = -1;    // LB only: highest LA step known complete (read-ahead)

  for (int s = 0; s < Tn; ++s) {
    // LA: issue x-fragment loads early (latency hides under acc init/x-GEMM)
    s8v bx[4][4];
    if (isA) {
#pragma unroll
      for (int m = 0; m < 4; ++m)
#pragma unroll
        for (int kt = 0; kt < 4; ++kt)
          bx[m][kt] = *(const s8v*)(xb + ((size_t)(m * 16 + rl) * Tn + s) * INn + w * 128 + kt * 32 + kg * 8);
    }

    f4v acc[4][4];
#pragma unroll
    for (int m = 0; m < 4; ++m)
#pragma unroll
      for (int g = 0; g < 4; ++g) acc[m][g] = (f4v){0.f, 0.f, 0.f, 0.f};

    // deep-ring slots (no address reuse within 256+ steps => L2-cache safe)
    const unsigned short* hsrc = isA ? (h0r + (size_t)((s - 1) & 511) * 65536)
                                     : (h1r + (size_t)((s - 1) & 255) * 65536);
    const unsigned short* asrc = h0r + (size_t)(s & 511) * 65536;  // LB input h0[s]

    if (isA) {
      // x-GEMM BEFORE the spins: pure-input work off the critical path
#pragma unroll
      for (int kt = 0; kt < 4; ++kt) {
        s8v f4[4] = { bx[0][kt], bx[1][kt], bx[2][kt], bx[3][kt] };
        mfma3(acc, wx[0][kt], wx[1][kt], wx[2][kt], f4, 2);
      }
      // gates: own-chain CA[s-1]; ring-overwrite guard CB[s-256]
      if (tid < 8)                      spin_ge(&CA[CDW(s - 1, tid)], 8);
      else if (tid < 16 && s >= 256)    spin_ge(&CB[CDW(s - 256, tid - 8)], 8);
      __syncthreads();
      VMWAIT(0);                             // clean vmcnt for counted pipe
      stream_gemm<3>(acc, wh_, hsrc, w, rl, kg);
    } else {
      // 1. CA[s] via read-ahead cache: 1 poll per ~32 steps in steady state
      if (tid < 8 && caDone < s) {
        int ra = s + 32; if (ra > Tn - 1) ra = Tn - 1;
        if (__hip_atomic_load(&CA[CDW(ra, tid)], __ATOMIC_RELAXED,
                              __HIP_MEMORY_SCOPE_AGENT) >= 8) {
          caDone = ra;
        } else {
          spin_ge(&CA[CDW(s, tid)], 8);
          caDone = s;
        }
      }
      __syncthreads();
      VMWAIT(0);                             // clean vmcnt for counted pipe
      // 2. a-GEMM BEFORE the CB spin: CB[s-1] flag propagates during this
      stream_gemm<2>(acc, wx, asrc, w, rl, kg);
      // 3. now gate on h1[s-1] (usually already set => single MALL read)
      if (tid < 8) spin_ge(&CB[CDW(s - 1, tid)], 8);
      __syncthreads();
      // 4. h-GEMM (stream_gemm<2> self-drained vmcnt; spins auto-waited)
      stream_gemm<3>(acc, wh_, hsrc, w, rl, kg);
    }

    // cross-wave K-combine (LDS)
#pragma unroll
    for (int d = 0; d < 4; ++d) if (d != w)
#pragma unroll
      for (int g = 0; g < 4; ++g) *(f4v*)&cmb[d][w][lane][g * 4] = acc[d][g];
    __syncthreads();
    f4v hsum[4];
#pragma unroll
    for (int g = 0; g < 4; ++g) {
      hsum[g] = acc[w][g];
#pragma unroll
      for (int src = 0; src < 4; ++src) if (src != w) hsum[g] += *(f4v*)&cmb[w][src][lane][g * 4];
    }

    // epilogue: gates + zoneout, state stays in hv registers
    us4v hb4;
#pragma unroll
    for (int rr = 0; rr < 4; ++rr) {
      float hp = hv[rr];
      float rg = 1.f / (1.f + __expf(-(hsum[0][rr] + bir[rr] + bhr[rr])));
      float zg = 1.f / (1.f + __expf(-(hsum[1][rr] + biz[rr] + bhz[rr])));
      float narg = hsum[2][rr] + bin[rr] + rg * (hsum[3][rr] + bhn[rr]);
      float e2 = __expf(2.f * narg);
      float ng = 1.f - 2.f / (e2 + 1.f);
      float nv = (1.f - zg) * ng + zg * hp;
      hv[rr] = 0.1f * hp + 0.9f * nv;
    }
    hb4[0] = f2bf(hv[0]); hb4[1] = f2bf(hv[1]); hb4[2] = f2bf(hv[2]); hb4[3] = f2bf(hv[3]);

    // broadcast bf16 h (write-through 8B atomics to deep ring), outputs (nt)
    if (isA) {
      st8c(h0r + (size_t)(s & 511) * 65536 + jt * 1024 + b * 16 + kg * 4, hb4);
      if (s == Tn - 1)
        __builtin_nontemporal_store(hv, (f4v*)(out + 67108864u + (size_t)b * Hn + j0));
    } else {
      st8c(h1r + (size_t)(s & 255) * 65536 + jt * 1024 + b * 16 + kg * 4, hb4);
      __builtin_nontemporal_store(hv, (f4v*)(out + ((size_t)b * Tn + s) * Hn + j0));
      if (s == Tn - 1)
        __builtin_nontemporal_store(hv, (f4v*)(out + 67108864u + 65536u + (size_t)b * Hn + j0));
    }
    // drain stores to coherence point, then relaxed flag add
    asm volatile("s_waitcnt vmcnt(0)" ::: "memory");
    __syncthreads();
    if (tid == 0) {
      int* C = isA ? CA : CB;
      __hip_atomic_fetch_add(&C[CDW(s, bank)], 1, __ATOMIC_RELAXED, __HIP_MEMORY_SCOPE_AGENT);
    }
  }
}

extern "C" void kernel_launch(void* const* d_in, const int* in_sizes, int n_in,
                              void* d_out, int out_size, void* d_ws, size_t ws_size,
                              hipStream_t stream) {
  (void)in_sizes; (void)n_in; (void)out_size; (void)ws_size;
  const float* x    = (const float*)d_in[0];
  const float* h0in = (const float*)d_in[1];
  const float* wih0 = (const float*)d_in[2];
  const float* whh0 = (const float*)d_in[3];
  const float* bih0 = (const float*)d_in[4];
  const float* bhh0 = (const float*)d_in[5];
  const float* wih1 = (const float*)d_in[6];
  const float* whh1 = (const float*)d_in[7];
  const float* bih1 = (const float*)d_in[8];
  const float* bhh1 = (const float*)d_in[9];
  float* out = (float*)d_out;
  char* ws = (char*)d_ws;

  cvt_bf16_kernel<<<2048, 256, 0, stream>>>(x, (unsigned short*)(ws + WS_XB), 33554432 / 4);
  init_all<<<528, 256, 0, stream>>>(h0in, ws);
  gru_persist<<<dim3(256), dim3(256), 0, stream>>>(
      h0in, wih0, whh0, bih0, bhh0, wih1, whh1, bih1, bhh1, out, ws);
}

// Round 3
// 10992.540 us; speedup vs baseline: 1.1029x; 1.1029x over previous
//
#include <hip/hip_runtime.h>

// ZoneoutGRU persistent kernel v10: B=64, T=1024, IN=512, H=1024, L=2, zo=0.1.
// 128 active blocks (64 LA = layer0, 64 LB = layer1), 256 thr (4 waves = K
// slices). Weights VGPR-resident, fp32 h state in registers. Deep h rings
// (v7): consumer reads are L2-cacheable (sc0), no stale-L2 hazard.
// v10 vs v7 (v9's backoff/reorder REVERTED — they regressed):
//  - H3: the 2-deep stream was latency-bound (~8 exposed RTTs/stream).
//    stream_gemm_deep pre-issues 24 loads (depth-6 fragment ring) and
//    consumes with descending counted vmcnt => ~1 exposed RTT + tail.
//    (Prior "depth-4 slower" verdict was pre-v7, all-MALL regime; in the
//    L2-cached regime deep issue is cheap.)
//  - LB drain decouple: st8c issued FIRST, out nt-store second, wait
//    vmcnt(1) => st8c acked (in-order retire), HBM write-ack off the chain.
//  - pads: no LDS, no barriers, rare per-wave poll (decontaminates
//    SQ_LDS_BANK_CONFLICT, which v8/v9 polluted).
// Sync protocol v3/v4 (proven) unchanged: relaxed agent atomics only, tight
// s_sleep(1) spins, banked counters, ring-overwrite guards.

#define Tn 1024
#define Hn 1024
#define INn 512

typedef short s8v __attribute__((ext_vector_type(8)));
typedef float f4v __attribute__((ext_vector_type(4)));
typedef unsigned short us4v __attribute__((ext_vector_type(4)));
typedef unsigned long long ull;

// ws layout (bytes) — total 168,837,120 (~161 MB)
#define WS_XB  0u           // x bf16 [64][1024][512]            = 67,108,864
#define WS_H0R 67108864u    // ring [512][ktile64][b64][16] bf16 = 67,108,864
#define WS_H1R 134217728u   // ring [256][ktile64][b64][16] bf16 = 33,554,432
#define WS_CA  167772160u   // [1040][128] int (8 banks @ 64B)   =    532,480
#define WS_CB  168304640u   // same                              =    532,480

__device__ __forceinline__ unsigned short f2bf(float f) {
  unsigned int u = __float_as_uint(f);
  u += 0x7fffu + ((u >> 16) & 1u);
  return (unsigned short)(u >> 16);
}

__device__ __forceinline__ s8v pack8(const float* p) {
  float4 a = *(const float4*)p;
  float4 b = *(const float4*)(p + 4);
  s8v r;
  r[0] = (short)f2bf(a.x); r[1] = (short)f2bf(a.y);
  r[2] = (short)f2bf(a.z); r[3] = (short)f2bf(a.w);
  r[4] = (short)f2bf(b.x); r[5] = (short)f2bf(b.y);
  r[6] = (short)f2bf(b.z); r[7] = (short)f2bf(b.w);
  return r;
}

// producer store: relaxed agent-scope 8B atomic = write-through to MALL (v3+)
__device__ __forceinline__ void st8c(unsigned short* p, us4v v) {
  union { us4v v; ull u; } c; c.v = v;
  __hip_atomic_store((ull*)p, c.u, __ATOMIC_RELAXED, __HIP_MEMORY_SCOPE_AGENT);
}

// nt store via asm: ordered against other asm/memory ops (drain-count safety)
__device__ __forceinline__ void stnt16(float* p, f4v v) {
  asm volatile("global_store_dwordx4 %0, %1, off nt" :: "v"(p), "v"(v) : "memory");
}

// consumer loads: sc0 only — L1-bypass, L2-CACHEABLE (deep ring => no stale)
__device__ __forceinline__ void issue4c(s8v* f, const unsigned short* src,
                                        int kt, int w, int rl, int kg) {
#pragma unroll
  for (int m = 0; m < 4; ++m) {
    const unsigned short* p = src + (size_t)(w * 16 + kt * 2 + (kg >> 1)) * 1024
                              + (m * 16 + rl) * 16 + (kg & 1) * 8;
    asm volatile("global_load_dwordx4 %0, %1, off sc0"
                 : "=v"(f[m]) : "v"(p) : "memory");
  }
}

template<int N> __device__ __forceinline__ void vmwait() {
  asm volatile("s_waitcnt vmcnt(%0)" :: "i"(N) : "memory");
  __builtin_amdgcn_sched_barrier(0);
}

__device__ __forceinline__ void mfma3(f4v (*acc)[4], s8v w0, s8v w1, s8v w2,
                                      const s8v f[4], const int gl) {
#pragma unroll
  for (int m = 0; m < 4; ++m) {
    acc[m][0]  = __builtin_amdgcn_mfma_f32_16x16x32_bf16(w0, f[m], acc[m][0], 0, 0, 0);
    acc[m][1]  = __builtin_amdgcn_mfma_f32_16x16x32_bf16(w1, f[m], acc[m][1], 0, 0, 0);
    acc[m][gl] = __builtin_amdgcn_mfma_f32_16x16x32_bf16(w2, f[m], acc[m][gl], 0, 0, 0);
  }
}

// v10 deep-pipelined stream GEMM: pre-issue 24 loads (depth-6 fragment ring),
// consume with descending counted vmcnt, re-issue after consume (WAR-safe:
// consume precedes re-issue of the same buffer in program order).
// Precondition: vmcnt == 0 on entry; self-drains on exit (last wait is 0).
template<int GL>
__device__ __forceinline__ void stream_gemm_deep(f4v (*acc)[4], const s8v (*wgt)[8],
    const unsigned short* src, int w, int rl, int kg) {
  s8v f[6][4];
#pragma unroll
  for (int kt = 0; kt < 6; ++kt) issue4c(f[kt], src, kt, w, rl, kg);
  vmwait<20>(); mfma3(acc, wgt[0][0], wgt[1][0], wgt[2][0], f[0], GL);
  issue4c(f[0], src, 6, w, rl, kg);
  vmwait<20>(); mfma3(acc, wgt[0][1], wgt[1][1], wgt[2][1], f[1], GL);
  issue4c(f[1], src, 7, w, rl, kg);
  vmwait<20>(); mfma3(acc, wgt[0][2], wgt[1][2], wgt[2][2], f[2], GL);
  vmwait<16>(); mfma3(acc, wgt[0][3], wgt[1][3], wgt[2][3], f[3], GL);
  vmwait<12>(); mfma3(acc, wgt[0][4], wgt[1][4], wgt[2][4], f[4], GL);
  vmwait<8>();  mfma3(acc, wgt[0][5], wgt[1][5], wgt[2][5], f[5], GL);
  vmwait<4>();  mfma3(acc, wgt[0][6], wgt[1][6], wgt[2][6], f[0], GL);
  vmwait<0>();  mfma3(acc, wgt[0][7], wgt[1][7], wgt[2][7], f[1], GL);
}

__global__ void cvt_bf16_kernel(const float* __restrict__ src,
                                unsigned short* __restrict__ dst, int n4) {
  int i = blockIdx.x * blockDim.x + threadIdx.x;
  int st = gridDim.x * blockDim.x;
  for (; i < n4; i += st) {
    const float4 v = *(const float4*)(src + 4 * (size_t)i);
    us4v o;
    o[0] = f2bf(v.x); o[1] = f2bf(v.y); o[2] = f2bf(v.z); o[3] = f2bf(v.w);
    *(us4v*)(dst + 4 * (size_t)i) = o;
  }
}

__global__ void init_all(const float* __restrict__ h0in, char* __restrict__ ws) {
  int i = blockIdx.x * blockDim.x + threadIdx.x;   // grid 528*256 = 135168
  unsigned short* h0r = (unsigned short*)(ws + WS_H0R);
  unsigned short* h1r = (unsigned short*)(ws + WS_H1R);
  int* CA = (int*)(ws + WS_CA);
  int* CB = (int*)(ws + WS_CB);
  if (i < 65536) {
    int b = i >> 10, h = i & 1023;
    int off = (h >> 4) * 1024 + b * 16 + (h & 15);
    h0r[511 * 65536 + off] = f2bf(h0in[i]);          // slot for step -1
    h1r[255 * 65536 + off] = f2bf(h0in[65536 + i]);  // slot for step -1
  }
  if (i < 133120) {
    int v = ((i >> 7) < 16 && (i & 15) == 0) ? 8 : 0;
    CA[i] = v; CB[i] = v;
  }
}

// v7-proven tight spin: s_sleep(1) cadence, relaxed agent loads
__device__ __forceinline__ void spin_ge(int* p, int target) {
  int tries = 0;
  while (__hip_atomic_load(p, __ATOMIC_RELAXED, __HIP_MEMORY_SCOPE_AGENT) < target) {
    __builtin_amdgcn_s_sleep(1);
    if (++tries > (1 << 22)) break;   // fail visibly, never hang
  }
}

// counter dword index for step s (>= -16), bank k
#define CDW(s, k) (((s) + 16) * 128 + (k) * 16)

__global__ __launch_bounds__(256, 1) void gru_persist(
    const float* __restrict__ h0in,
    const float* __restrict__ wih0, const float* __restrict__ whh0,
    const float* __restrict__ bih0, const float* __restrict__ bhh0,
    const float* __restrict__ wih1, const float* __restrict__ whh1,
    const float* __restrict__ bih1, const float* __restrict__ bhh1,
    float* __restrict__ out, char* __restrict__ ws)
{
  const unsigned short* xb = (const unsigned short*)(ws + WS_XB);
  unsigned short* h0r = (unsigned short*)(ws + WS_H0R);
  unsigned short* h1r = (unsigned short*)(ws + WS_H1R);
  int* CA = (int*)(ws + WS_CA);
  int* CB = (int*)(ws + WS_CB);

  const int blk = blockIdx.x;
  const int tid = threadIdx.x;

  if (blk >= 128) {
    // busy-clock pad (insurance). v10: NO LDS, NO barriers — each wave
    // independently polls one counter line every ~4k cy and exits when the
    // final LB step is flagged. Keeps SQ_LDS_BANK_CONFLICT clean.
    const int myb = blk & 7;
    float a0 = 1.0f + (float)tid * 1e-6f, a1 = a0 + 0.25f;
    float a2 = a0 + 0.5f, a3 = a0 + 0.75f;
    const float mm = 0.99999988f, cc = 1e-7f;
    int run = 1;
    for (int it = 0; it < (1 << 17) && run; ++it) {
#pragma unroll
      for (int u = 0; u < 256; ++u) {
        a0 = __builtin_fmaf(a0, mm, cc); a1 = __builtin_fmaf(a1, mm, cc);
        a2 = __builtin_fmaf(a2, mm, cc); a3 = __builtin_fmaf(a3, mm, cc);
      }
      if ((it & 7) == 0 &&
          __hip_atomic_load(&CB[CDW(Tn - 1, myb)], __ATOMIC_RELAXED,
                            __HIP_MEMORY_SCOPE_AGENT) >= 8)
        run = 0;
    }
    asm volatile("" :: "v"(a0), "v"(a1), "v"(a2), "v"(a3));  // keep chains live
    return;
  }

  const bool isA = blk < 64;
  const int jt = blk & 63, jj = jt * 16;
  const int w = tid >> 6;                    // wave = K-slice = owner m-group
  const int lane = tid & 63;
  const int rl = lane & 15, kg = lane >> 4;
  const int bank = blk & 7;

  __shared__ float cmb[4][4][64][20];        // stride 80B: conflict-free (r6)

  const int b = w * 16 + rl;                 // owner batch row (epilogue)
  const int j0 = jj + kg * 4;                // owner j base (epilogue)

  // ---- VGPR-resident weights ----
  const float* Wi = isA ? wih0 : wih1;
  const float* Wh = isA ? whh0 : whh1;
  const float* bi = isA ? bih0 : bih1;
  const float* bh = isA ? bhh0 : bhh1;
  const int Kx = isA ? INn : Hn;             // input-side K
  s8v wx[3][8], wh_[3][8];
  const int nkx = Kx / 128;                  // 4 (LA) or 8 (LB) k-tiles of 32
#pragma unroll
  for (int g = 0; g < 3; ++g) {
    for (int kt = 0; kt < nkx; ++kt)
      wx[g][kt] = pack8(Wi + (size_t)(g * 1024 + jj + rl) * Kx + w * (Kx / 4) + kt * 32 + kg * 8);
#pragma unroll
    for (int kt = 0; kt < 8; ++kt)
      wh_[g][kt] = pack8(Wh + (size_t)(g * 1024 + jj + rl) * Hn + w * 256 + kt * 32 + kg * 8);
  }
  const f4v bir = *(const f4v*)(bi + j0),        bhr = *(const f4v*)(bh + j0);
  const f4v biz = *(const f4v*)(bi + 1024 + j0), bhz = *(const f4v*)(bh + 1024 + j0);
  const f4v bin = *(const f4v*)(bi + 2048 + j0), bhn = *(const f4v*)(bh + 2048 + j0);

  // ---- register-resident fp32 hidden state (this thread's (b, j0..j0+3)) ----
  f4v hv = *(const f4v*)(h0in + (isA ? 0u : 65536u) + (size_t)b * Hn + j0);

  for (int s = 0; s < Tn; ++s) {
    // 1. LA: prefetch x fragments (plain cached loads, v4-proven) before spin
    s8v bx[4][4];
    if (isA) {
#pragma unroll
      for (int m = 0; m < 4; ++m)
#pragma unroll
        for (int kt = 0; kt < 4; ++kt)
          bx[m][kt] = *(const s8v*)(xb + ((size_t)(m * 16 + rl) * Tn + s) * INn + w * 128 + kt * 32 + kg * 8);
    }
    // 2. spin on banked counters (8 parallel pollers each; relaxed, MALL)
    if (isA) {
      if (tid < 8)                      spin_ge(&CA[CDW(s - 1, tid)], 8);
      else if (tid < 16 && s >= 256)    spin_ge(&CB[CDW(s - 256, tid - 8)], 8);
    } else {
      if (tid < 8)                      spin_ge(&CA[CDW(s, tid)], 8);
      else if (tid < 16)                spin_ge(&CB[CDW(s - 1, tid - 8)], 8);
    }
    __syncthreads();
    vmwait<0>();                             // clean baseline for counted pipe

    f4v acc[4][4];
#pragma unroll
    for (int m = 0; m < 4; ++m)
#pragma unroll
      for (int g = 0; g < 4; ++g) acc[m][g] = (f4v){0.f, 0.f, 0.f, 0.f};

    // deep-ring slots (no address reuse within 256+ steps => L2-cache safe)
    const unsigned short* hsrc = isA ? (h0r + (size_t)((s - 1) & 511) * 65536)
                                     : (h1r + (size_t)((s - 1) & 255) * 65536);
    const unsigned short* asrc = h0r + (size_t)(s & 511) * 65536;  // LB input h0[s]

    if (isA) {
      // 3a. x-GEMM from registers
#pragma unroll
      for (int kt = 0; kt < 4; ++kt) {
        s8v f4[4] = { bx[0][kt], bx[1][kt], bx[2][kt], bx[3][kt] };
        mfma3(acc, wx[0][kt], wx[1][kt], wx[2][kt], f4, 2);
      }
      // 3b. hidden stream, deep-pipelined (~1 exposed RTT)
      stream_gemm_deep<3>(acc, wh_, hsrc, w, rl, kg);
    } else {
      // 3. a-stream then h-stream, each deep-pipelined (self-draining)
      stream_gemm_deep<2>(acc, wx, asrc, w, rl, kg);
      stream_gemm_deep<3>(acc, wh_, hsrc, w, rl, kg);
    }

    // 4. cross-wave K-combine (LDS)
#pragma unroll
    for (int d = 0; d < 4; ++d) if (d != w)
#pragma unroll
      for (int g = 0; g < 4; ++g) *(f4v*)&cmb[d][w][lane][g * 4] = acc[d][g];
    __syncthreads();
    f4v hsum[4];
#pragma unroll
    for (int g = 0; g < 4; ++g) {
      hsum[g] = acc[w][g];
#pragma unroll
      for (int src = 0; src < 4; ++src) if (src != w) hsum[g] += *(f4v*)&cmb[w][src][lane][g * 4];
    }

    // 5. epilogue: gates + zoneout, state stays in hv registers
    us4v hb4;
#pragma unroll
    for (int rr = 0; rr < 4; ++rr) {
      float hp = hv[rr];
      float rg = 1.f / (1.f + __expf(-(hsum[0][rr] + bir[rr] + bhr[rr])));
      float zg = 1.f / (1.f + __expf(-(hsum[1][rr] + biz[rr] + bhz[rr])));
      float narg = hsum[2][rr] + bin[rr] + rg * (hsum[3][rr] + bhn[rr]);
      float e2 = __expf(2.f * narg);
      float ng = 1.f - 2.f / (e2 + 1.f);
      float nv = (1.f - zg) * ng + zg * hp;
      hv[rr] = 0.1f * hp + 0.9f * nv;
    }
    hb4[0] = f2bf(hv[0]); hb4[1] = f2bf(hv[1]); hb4[2] = f2bf(hv[2]); hb4[3] = f2bf(hv[3]);

    // 6. broadcast bf16 h (write-through 8B atomics, issued FIRST), then out
    //    nt-stores; 7. counted drain: wait only until st8c is acked (in-order
    //    retire => vmcnt(1) leaves just the younger out-store in flight).
    if (isA) {
      st8c(h0r + (size_t)(s & 511) * 65536 + jt * 1024 + b * 16 + kg * 4, hb4);
      if (s == Tn - 1)
        stnt16(out + 67108864u + (size_t)b * Hn + j0, hv);
      vmwait<0>();                           // st8c (+final store) acked
    } else {
      st8c(h1r + (size_t)(s & 255) * 65536 + jt * 1024 + b * 16 + kg * 4, hb4);
      stnt16(out + ((size_t)b * Tn + s) * Hn + j0, hv);
      if (s == Tn - 1) {
        stnt16(out + 67108864u + 65536u + (size_t)b * Hn + j0, hv);
        vmwait<0>();
      } else {
        vmwait<1>();                         // st8c acked; out-store off-chain
      }
    }
    __syncthreads();
    if (tid == 0) {
      int* C = isA ? CA : CB;
      __hip_atomic_fetch_add(&C[CDW(s, bank)], 1, __ATOMIC_RELAXED, __HIP_MEMORY_SCOPE_AGENT);
    }
  }
}

extern "C" void kernel_launch(void* const* d_in, const int* in_sizes, int n_in,
                              void* d_out, int out_size, void* d_ws, size_t ws_size,
                              hipStream_t stream) {
  (void)in_sizes; (void)n_in; (void)out_size; (void)ws_size;
  const float* x    = (const float*)d_in[0];
  const float* h0in = (const float*)d_in[1];
  const float* wih0 = (const float*)d_in[2];
  const float* whh0 = (const float*)d_in[3];
  const float* bih0 = (const float*)d_in[4];
  const float* bhh0 = (const float*)d_in[5];
  const float* wih1 = (const float*)d_in[6];
  const float* whh1 = (const float*)d_in[7];
  const float* bih1 = (const float*)d_in[8];
  const float* bhh1 = (const float*)d_in[9];
  float* out = (float*)d_out;
  char* ws = (char*)d_ws;

  cvt_bf16_kernel<<<2048, 256, 0, stream>>>(x, (unsigned short*)(ws + WS_XB), 33554432 / 4);
  init_all<<<528, 256, 0, stream>>>(h0in, ws);
  gru_persist<<<dim3(256), dim3(256), 0, stream>>>(
      h0in, wih0, whh0, bih0, bhh0, wih1, whh1, bih1, bhh1, out, ws);
}